// Round 1
// baseline (2388.458 us; speedup 1.0000x reference)
//
#include <hip/hip_runtime.h>
#include <hip/hip_bf16.h>

// Problem constants (Head_60421599920770): B=32, T=2048, C=256, HS=64
#define NB 32
#define NT 2048
#define NC 256
#define NH 64

static constexpr float SCALE = 0.125f;   // HS^-0.5 = 1/8
static constexpr float LNEG  = -1e9f;

// ---------------------------------------------------------------------------
// Kernel A: QKV projection. Each block: 16 rows of X (staged in LDS),
// 256 threads; thread (r=tid>>6 base, d=tid&63) computes Q/K/V for 4 rows.
// ---------------------------------------------------------------------------
__global__ __launch_bounds__(256) void qkv_kernel(
    const float* __restrict__ X,
    const float* __restrict__ Wq, const float* __restrict__ Wk,
    const float* __restrict__ Wv,
    float* __restrict__ Q, float* __restrict__ K, float* __restrict__ V)
{
    __shared__ float x_lds[16][NC];
    const int row0 = blockIdx.x * 16;      // flat row = b*NT + t (16 | NT, no batch crossing)
    const int tid  = threadIdx.x;
    #pragma unroll
    for (int i = 0; i < 4; ++i) {
        int e  = tid + i * 256;            // float4 index within 16x256 tile
        int r  = e >> 6;
        int c4 = (e & 63) << 2;
        *(float4*)&x_lds[r][c4] =
            *(const float4*)&X[(size_t)(row0 + r) * NC + c4];
    }
    __syncthreads();
    const int d     = tid & 63;
    const int rbase = tid >> 6;            // 0..3 ; rows rbase, rbase+4, +8, +12
    float aq[4] = {0.f,0.f,0.f,0.f};
    float ak[4] = {0.f,0.f,0.f,0.f};
    float av[4] = {0.f,0.f,0.f,0.f};
    for (int c = 0; c < NC; ++c) {
        float wq = Wq[c * NH + d];         // coalesced 256B/wave; L2-resident
        float wk = Wk[c * NH + d];
        float wv = Wv[c * NH + d];
        #pragma unroll
        for (int i = 0; i < 4; ++i) {
            float xv = x_lds[rbase + 4 * i][c];   // wave-uniform -> LDS broadcast
            aq[i] = fmaf(xv, wq, aq[i]);
            ak[i] = fmaf(xv, wk, ak[i]);
            av[i] = fmaf(xv, wv, av[i]);
        }
    }
    #pragma unroll
    for (int i = 0; i < 4; ++i) {
        size_t o = (size_t)(row0 + rbase + 4 * i) * NH + d;
        Q[o] = aq[i]; K[o] = ak[i]; V[o] = av[i];
    }
}

// ---------------------------------------------------------------------------
// Kernel B: mean over all T of V, per batch. Needed for degenerate rows where
// every causal key is padding-masked: reference softmax is then uniform over
// ALL 2048 keys -> out = mean_v[b].
// ---------------------------------------------------------------------------
__global__ __launch_bounds__(1024) void meanv_kernel(
    const float* __restrict__ V, float* __restrict__ MV)
{
    __shared__ float red[16][NH];
    const int b   = blockIdx.x;
    const int tid = threadIdx.x;
    const int d   = tid & 63;
    const int g   = tid >> 6;              // 0..15
    float s = 0.f;
    for (int t = g; t < NT; t += 16)
        s += V[((size_t)b * NT + t) * NH + d];
    red[g][d] = s;
    __syncthreads();
    if (g == 0) {
        float tot = 0.f;
        #pragma unroll
        for (int i = 0; i < 16; ++i) tot += red[i][d];
        MV[b * NH + d] = tot * (1.0f / NT);
    }
}

// ---------------------------------------------------------------------------
// Kernel C: causal flash attention with padding mask + degenerate fixup.
// 1024 threads = 16 waves; block owns 64 consecutive queries; wave owns 4.
// K tile stored TRANSPOSED [d][j] pad 65 (conflict-free store & read),
// V row-major [j][d] pad 65. Lane j = key index for QK^T; lane = output dim
// for PV (p broadcast via shfl).
// ---------------------------------------------------------------------------
#define QB 64
#define KB 64

__global__ __launch_bounds__(1024) void attn_kernel(
    const float* __restrict__ Q, const float* __restrict__ K,
    const float* __restrict__ V, const int* __restrict__ mask,
    const float* __restrict__ MV, float* __restrict__ Out)
{
    __shared__ float q_lds[QB][NH];        // broadcast reads: no pad needed
    __shared__ float kt_lds[NH][KB + 1];   // transposed K tile
    __shared__ float v_lds[KB][KB + 1];

    const int bq   = blockIdx.x;
    const int b    = bq >> 5;              // NT/QB = 32 query-groups per batch
    const int q0   = (bq & 31) * QB;
    const int tid  = threadIdx.x;
    const int wid  = tid >> 6;
    const int lane = tid & 63;

    // stage the block's 64 Q rows
    const float* Qb = Q + ((size_t)b * NT + q0) * NH;
    #pragma unroll
    for (int i = 0; i < 4; ++i) {
        int e = tid + i * 1024;
        q_lds[e >> 6][e & 63] = Qb[e];
    }

    const int qrow = wid * 4;              // local base row of this wave
    const int tq0  = q0 + qrow;
    float m_r[4], l_r[4], o_r[4], p_r[4];
    #pragma unroll
    for (int qq = 0; qq < 4; ++qq) { m_r[qq] = -3.0e38f; l_r[qq] = 0.f; o_r[qq] = 0.f; }

    const float* Kb = K + (size_t)b * NT * NH;
    const float* Vb = V + (size_t)b * NT * NH;
    const int*   Mb = mask + b * NT;

    const int nt = (q0 >> 6) + 1;          // tiles 0..q0/64 cover keys <= q0+63
    for (int kt = 0; kt < nt; ++kt) {
        const int k0 = kt * KB;
        __syncthreads();                   // previous tile fully consumed
        {
            int r  = tid >> 4;
            int c4 = (tid & 15) << 2;
            float4 kv = *(const float4*)&Kb[(size_t)(k0 + r) * NH + c4];
            float4 vv = *(const float4*)&Vb[(size_t)(k0 + r) * NH + c4];
            kt_lds[c4 + 0][r] = kv.x; kt_lds[c4 + 1][r] = kv.y;
            kt_lds[c4 + 2][r] = kv.z; kt_lds[c4 + 3][r] = kv.w;
            v_lds[r][c4 + 0]  = vv.x; v_lds[r][c4 + 1]  = vv.y;
            v_lds[r][c4 + 2]  = vv.z; v_lds[r][c4 + 3]  = vv.w;
        }
        __syncthreads();

        // QK^T: lane j = key k0+lane; 4 queries per wave
        float s0 = 0.f, s1 = 0.f, s2 = 0.f, s3 = 0.f;
        #pragma unroll 8
        for (int d = 0; d < NH; ++d) {
            float kv = kt_lds[d][lane];               // lane-consecutive: conflict-free
            s0 = fmaf(q_lds[qrow + 0][d], kv, s0);    // wave-uniform: broadcast
            s1 = fmaf(q_lds[qrow + 1][d], kv, s1);
            s2 = fmaf(q_lds[qrow + 2][d], kv, s2);
            s3 = fmaf(q_lds[qrow + 3][d], kv, s3);
        }

        const int kk = k0 + lane;
        const int mv = Mb[kk];                        // coalesced, L2-resident
        float sv[4] = {s0, s1, s2, s3};
        #pragma unroll
        for (int qq = 0; qq < 4; ++qq) {
            float s = sv[qq] * SCALE;
            if (kk > tq0 + qq || mv == 0) s = LNEG;   // exact -1e9, like reference
            float tm = s;
            #pragma unroll
            for (int off = 32; off > 0; off >>= 1)
                tm = fmaxf(tm, __shfl_xor(tm, off));
            float mnew  = fmaxf(m_r[qq], tm);
            float alpha = __expf(m_r[qq] - mnew);     // exp(-huge)=0 on first tile
            float p     = __expf(s - mnew);           // masked: exp(-1e9-m)=0 (or 1 if all masked)
            float ps = p;
            #pragma unroll
            for (int off = 32; off > 0; off >>= 1)
                ps += __shfl_xor(ps, off);
            m_r[qq] = mnew;
            l_r[qq] = l_r[qq] * alpha + ps;
            o_r[qq] *= alpha;
            p_r[qq] = p;
        }

        // PV: lane owns output dim; p_j broadcast from lane j
        #pragma unroll 4
        for (int j = 0; j < KB; ++j) {
            float vv = v_lds[j][lane];                // lane-consecutive: conflict-free
            o_r[0] = fmaf(__shfl(p_r[0], j), vv, o_r[0]);
            o_r[1] = fmaf(__shfl(p_r[1], j), vv, o_r[1]);
            o_r[2] = fmaf(__shfl(p_r[2], j), vv, o_r[2]);
            o_r[3] = fmaf(__shfl(p_r[3], j), vv, o_r[3]);
        }
    }

    // epilogue: degenerate rows (all causal keys padding-masked -> m == -1e9
    // exactly; real scores are N(0,1), never below -100) get mean over ALL V.
    float* Ob = Out + ((size_t)b * NT + tq0) * NH;
    #pragma unroll
    for (int qq = 0; qq < 4; ++qq) {
        float val = (m_r[qq] <= -5.0e8f) ? MV[b * NH + lane]
                                         : o_r[qq] / l_r[qq];
        Ob[qq * NH + lane] = val;
    }
}

// ---------------------------------------------------------------------------
extern "C" void kernel_launch(void* const* d_in, const int* in_sizes, int n_in,
                              void* d_out, int out_size, void* d_ws, size_t ws_size,
                              hipStream_t stream)
{
    const float* X  = (const float*)d_in[0];   // q_input (B,T,C) fp32
    const float* Wq = (const float*)d_in[1];   // (C,HS) fp32
    const float* Wk = (const float*)d_in[2];
    const float* Wv = (const float*)d_in[3];
    const int*   M  = (const int*)d_in[4];     // attn_mask (B,T) as int32
    float* out = (float*)d_out;                // (B,T,HS) fp32

    // workspace: Q,K,V fp32 (16MB each) + mean_v (8KB) = ~50.3MB
    float* Qp = (float*)d_ws;
    float* Kp = Qp + (size_t)NB * NT * NH;
    float* Vp = Kp + (size_t)NB * NT * NH;
    float* MVp = Vp + (size_t)NB * NT * NH;

    qkv_kernel<<<NB * NT / 16, 256, 0, stream>>>(X, Wq, Wk, Wv, Qp, Kp, Vp);
    meanv_kernel<<<NB, 1024, 0, stream>>>(Vp, MVp);
    attn_kernel<<<NB * NT / QB, 1024, 0, stream>>>(Qp, Kp, Vp, M, MVp, out);
}

// Round 2
// 249.740 us; speedup vs baseline: 9.5638x; 9.5638x over previous
//
#include <hip/hip_runtime.h>
#include <hip/hip_bf16.h>

// Problem constants (Head_60421599920770): B=32, T=2048, C=256, HS=64
#define NB 32
#define NT 2048
#define NC 256
#define NH 64
#define QB 64
#define KB 64

typedef __attribute__((ext_vector_type(8))) short bf16x8;   // 8 bf16 = 4 VGPRs
typedef __attribute__((ext_vector_type(4))) float f32x4;    // MFMA C/D

static constexpr float SCALE = 0.125f;   // HS^-0.5
static constexpr float LNEG  = -1e9f;

static __device__ inline short f2b(float x) {
    __hip_bfloat16 h = __float2bfloat16(x);
    return *reinterpret_cast<short*>(&h);
}
static __device__ inline float b2f(short s) {
    unsigned int u = ((unsigned int)(unsigned short)s) << 16;
    float f; __builtin_memcpy(&f, &u, 4); return f;
}

// ---------------------------------------------------------------------------
// Kernel A: QKV projection (fp32 FMA), outputs bf16.
// Q, K row-major (b*T+t, d); V written TRANSPOSED as Vt[(b*NH+d)*NT + t]
// so the attention kernel's PV B-fragment is a contiguous 16B LDS read.
// ---------------------------------------------------------------------------
__global__ __launch_bounds__(256) void qkv_kernel(
    const float* __restrict__ X,
    const float* __restrict__ Wq, const float* __restrict__ Wk,
    const float* __restrict__ Wv,
    __hip_bfloat16* __restrict__ Q, __hip_bfloat16* __restrict__ K,
    __hip_bfloat16* __restrict__ Vt)
{
    __shared__ float x_lds[16][NC];
    __shared__ float v_s[16][NH + 1];
    const int row0 = blockIdx.x * 16;      // 16 | NT: no batch crossing
    const int tid  = threadIdx.x;
    #pragma unroll
    for (int i = 0; i < 4; ++i) {
        int e  = tid + i * 256;
        int r  = e >> 6;
        int c4 = (e & 63) << 2;
        *(float4*)&x_lds[r][c4] =
            *(const float4*)&X[(size_t)(row0 + r) * NC + c4];
    }
    __syncthreads();
    const int d     = tid & 63;
    const int rbase = tid >> 6;            // rows rbase, +4, +8, +12
    float aq[4] = {0.f,0.f,0.f,0.f};
    float ak[4] = {0.f,0.f,0.f,0.f};
    float av[4] = {0.f,0.f,0.f,0.f};
    for (int c = 0; c < NC; ++c) {
        float wq = Wq[c * NH + d];
        float wk = Wk[c * NH + d];
        float wv = Wv[c * NH + d];
        #pragma unroll
        for (int i = 0; i < 4; ++i) {
            float xv = x_lds[rbase + 4 * i][c];
            aq[i] = fmaf(xv, wq, aq[i]);
            ak[i] = fmaf(xv, wk, ak[i]);
            av[i] = fmaf(xv, wv, av[i]);
        }
    }
    #pragma unroll
    for (int i = 0; i < 4; ++i) {
        int    lr = rbase + 4 * i;
        size_t o  = (size_t)(row0 + lr) * NH + d;
        Q[o] = __float2bfloat16(aq[i]);
        K[o] = __float2bfloat16(ak[i]);
        v_s[lr][d] = av[i];
    }
    __syncthreads();
    // transpose V block: 16 t x 64 d -> Vt rows d, 16 t each (short4 = 4 t)
    const int b  = row0 >> 11;             // /NT
    const int t0 = row0 & (NT - 1);
    const int dd = tid >> 2;
    const int tq = (tid & 3) * 4;
    short4 w;
    w.x = f2b(v_s[tq + 0][dd]);
    w.y = f2b(v_s[tq + 1][dd]);
    w.z = f2b(v_s[tq + 2][dd]);
    w.w = f2b(v_s[tq + 3][dd]);
    *reinterpret_cast<short4*>(&Vt[((size_t)b * NH + dd) * NT + t0 + tq]) = w;
}

// ---------------------------------------------------------------------------
// Kernel B: mean over all T of V (per batch, per d) from transposed Vt.
// Needed for fully-masked causal rows (reference softmax -> uniform over ALL keys).
// ---------------------------------------------------------------------------
__global__ __launch_bounds__(1024) void meanv_kernel(
    const __hip_bfloat16* __restrict__ Vt, float* __restrict__ MV)
{
    __shared__ float red[NH][17];
    const int b    = blockIdx.x;
    const int tid  = threadIdx.x;
    const int d    = tid >> 4;
    const int part = tid & 15;
    const __hip_bfloat16* row = Vt + ((size_t)b * NH + d) * NT;
    float s = 0.f;
    for (int t = part * 128; t < part * 128 + 128; t += 8) {
        bf16x8 v = *reinterpret_cast<const bf16x8*>(&row[t]);
        #pragma unroll
        for (int j = 0; j < 8; ++j) s += b2f(v[j]);
    }
    red[d][part] = s;
    __syncthreads();
    if (part == 0) {
        float tot = 0.f;
        #pragma unroll
        for (int i = 0; i < 16; ++i) tot += red[d][i];
        MV[b * NH + d] = tot * (1.0f / NT);
    }
}

// ---------------------------------------------------------------------------
// Kernel C: bf16 MFMA flash attention (16x16x32), causal + padding mask.
// 256 thr = 4 waves; block = 64 queries (16/wave); KV tiles of 64.
// Fragment layouts (gfx950, m89-verified): A row = lane&15, k=(lane>>4)*8+e;
// B col = lane&15, k=(lane>>4)*8+e; C/D col = lane&15, row=(lane>>4)*4+reg.
// ---------------------------------------------------------------------------
__global__ __launch_bounds__(256) void attn_kernel(
    const __hip_bfloat16* __restrict__ Q, const __hip_bfloat16* __restrict__ K,
    const __hip_bfloat16* __restrict__ Vt, const int* __restrict__ mask,
    const float* __restrict__ MV, float* __restrict__ Out)
{
    __shared__ __hip_bfloat16 k_lds[KB][NH + 8];       // [64][72] keys row-major
    __shared__ __hip_bfloat16 vt_lds[NH][KB + 8];      // [64][72] V transposed (d, k)
    __shared__ __hip_bfloat16 p_lds[4][16][KB + 8];    // per-wave P (16 q x 64 k)

    const int bq  = blockIdx.x;
    const int b   = bq >> 5;               // 32 q-groups per batch
    const int idx = bq & 31;
    // interleave short/long causal blocks for CU load balance
    const int qg  = (idx & 1) ? (31 - (idx >> 1)) : (idx >> 1);
    const int q0  = qg * QB;
    const int tid = threadIdx.x;
    const int wid = tid >> 6;
    const int lane = tid & 63;
    const int l15 = lane & 15;
    const int lg  = lane >> 4;

    const __hip_bfloat16* Kg = K  + (size_t)b * NT * NH;
    const __hip_bfloat16* Vg = Vt + (size_t)b * NH * NT;
    const int* Mb = mask + b * NT;

    // Q A-fragments: fixed for the whole kernel, kept in registers
    const int qrow_blk = q0 + wid * 16;
    bf16x8 qf0, qf1;
    {
        const __hip_bfloat16* Qr = Q + ((size_t)b * NT + qrow_blk + l15) * NH;
        qf0 = *reinterpret_cast<const bf16x8*>(&Qr[lg * 8]);
        qf1 = *reinterpret_cast<const bf16x8*>(&Qr[lg * 8 + 32]);
    }

    f32x4 o_acc[4];
    float m_r[4], l_r[4];
    #pragma unroll
    for (int dt = 0; dt < 4; ++dt) o_acc[dt] = (f32x4){0.f,0.f,0.f,0.f};
    #pragma unroll
    for (int r = 0; r < 4; ++r) { m_r[r] = -3.0e38f; l_r[r] = 0.f; }

    const int qbase = qrow_blk + lg * 4;   // query row for acc reg r: qbase + r

    const int ntiles = qg + 1;
    for (int kt = 0; kt < ntiles; ++kt) {
        const int k0 = kt * KB;
        __syncthreads();                   // previous tile fully consumed
        #pragma unroll
        for (int i = 0; i < 2; ++i) {      // stage K (row-major) + Vt (d-major)
            int e = tid + i * 256;
            int r = e >> 3, c = (e & 7) * 8;
            *reinterpret_cast<bf16x8*>(&k_lds[r][c]) =
                *reinterpret_cast<const bf16x8*>(&Kg[(size_t)(k0 + r) * NH + c]);
            *reinterpret_cast<bf16x8*>(&vt_lds[r][c]) =
                *reinterpret_cast<const bf16x8*>(&Vg[(size_t)r * NT + k0 + c]);
        }
        __syncthreads();

        // ---- QK^T: 4 j-tiles x 2 k-chunks ----
        f32x4 s[4];
        #pragma unroll
        for (int jt = 0; jt < 4; ++jt) s[jt] = (f32x4){0.f,0.f,0.f,0.f};
        #pragma unroll
        for (int jt = 0; jt < 4; ++jt) {
            bf16x8 kfa = *reinterpret_cast<const bf16x8*>(&k_lds[jt*16 + l15][lg*8]);
            bf16x8 kfb = *reinterpret_cast<const bf16x8*>(&k_lds[jt*16 + l15][lg*8 + 32]);
            s[jt] = __builtin_amdgcn_mfma_f32_16x16x32_bf16(qf0, kfa, s[jt], 0, 0, 0);
            s[jt] = __builtin_amdgcn_mfma_f32_16x16x32_bf16(qf1, kfb, s[jt], 0, 0, 0);
        }

        // ---- mask + online softmax ----
        int mv[4];
        #pragma unroll
        for (int jt = 0; jt < 4; ++jt) mv[jt] = Mb[k0 + jt*16 + l15];

        float sm[4][4];
        #pragma unroll
        for (int jt = 0; jt < 4; ++jt) {
            const int key = k0 + jt * 16 + l15;
            const bool mz = (mv[jt] == 0);
            #pragma unroll
            for (int r = 0; r < 4; ++r) {
                float v = s[jt][r] * SCALE;
                if (key > qbase + r || mz) v = LNEG;
                sm[jt][r] = v;
            }
        }
        #pragma unroll
        for (int r = 0; r < 4; ++r) {
            float tm = fmaxf(fmaxf(sm[0][r], sm[1][r]), fmaxf(sm[2][r], sm[3][r]));
            #pragma unroll
            for (int off = 1; off < 16; off <<= 1) tm = fmaxf(tm, __shfl_xor(tm, off));
            const float mnew = fmaxf(m_r[r], tm);
            const float al   = __expf(m_r[r] - mnew);
            m_r[r] = mnew;
            float rs = 0.f;
            #pragma unroll
            for (int jt = 0; jt < 4; ++jt) {
                float pv = __expf(sm[jt][r] - mnew);
                p_lds[wid][lg * 4 + r][jt * 16 + l15] = __float2bfloat16(pv);
                rs += pv;
            }
            #pragma unroll
            for (int off = 1; off < 16; off <<= 1) rs += __shfl_xor(rs, off);
            l_r[r] = l_r[r] * al + rs;
            #pragma unroll
            for (int dt = 0; dt < 4; ++dt) o_acc[dt][r] *= al;
        }

        // ---- PV: reload P as A-fragments (wave-private LDS, no block barrier) ----
        bf16x8 pa0 = *reinterpret_cast<const bf16x8*>(&p_lds[wid][l15][lg * 8]);
        bf16x8 pa1 = *reinterpret_cast<const bf16x8*>(&p_lds[wid][l15][lg * 8 + 32]);
        #pragma unroll
        for (int dt = 0; dt < 4; ++dt) {
            bf16x8 vfa = *reinterpret_cast<const bf16x8*>(&vt_lds[dt*16 + l15][lg*8]);
            bf16x8 vfb = *reinterpret_cast<const bf16x8*>(&vt_lds[dt*16 + l15][lg*8 + 32]);
            o_acc[dt] = __builtin_amdgcn_mfma_f32_16x16x32_bf16(pa0, vfa, o_acc[dt], 0, 0, 0);
            o_acc[dt] = __builtin_amdgcn_mfma_f32_16x16x32_bf16(pa1, vfb, o_acc[dt], 0, 0, 0);
        }
    }

    // ---- epilogue: normalize; degenerate rows (all causal keys masked) -> mean V ----
    float* Ob = Out + (size_t)b * NT * NH;
    #pragma unroll
    for (int r = 0; r < 4; ++r) {
        const int  qrow  = qbase + r;
        const bool degen = (m_r[r] <= -5.0e8f);
        const float inv  = degen ? 0.f : 1.0f / l_r[r];
        #pragma unroll
        for (int dt = 0; dt < 4; ++dt) {
            const int d = dt * 16 + l15;
            float val = degen ? MV[b * NH + d] : o_acc[dt][r] * inv;
            Ob[(size_t)qrow * NH + d] = val;
        }
    }
}

// ---------------------------------------------------------------------------
extern "C" void kernel_launch(void* const* d_in, const int* in_sizes, int n_in,
                              void* d_out, int out_size, void* d_ws, size_t ws_size,
                              hipStream_t stream)
{
    const float* X  = (const float*)d_in[0];   // q_input (B,T,C) fp32
    const float* Wq = (const float*)d_in[1];
    const float* Wk = (const float*)d_in[2];
    const float* Wv = (const float*)d_in[3];
    const int*   M  = (const int*)d_in[4];     // attn_mask (B,T) int32
    float* out = (float*)d_out;                // (B,T,HS) fp32

    // workspace: Q,K,Vt bf16 (8MB each) + mean_v f32 (8KB)
    __hip_bfloat16* Qp = (__hip_bfloat16*)d_ws;
    __hip_bfloat16* Kp = Qp + (size_t)NB * NT * NH;
    __hip_bfloat16* Vp = Kp + (size_t)NB * NT * NH;
    float* MVp = (float*)(Vp + (size_t)NB * NT * NH);

    qkv_kernel<<<NB * NT / 16, 256, 0, stream>>>(X, Wq, Wk, Wv, Qp, Kp, Vp);
    meanv_kernel<<<NB, 1024, 0, stream>>>(Vp, MVp);
    attn_kernel<<<NB * NT / QB, 256, 0, stream>>>(Qp, Kp, Vp, M, MVp, out);
}

// Round 3
// 165.419 us; speedup vs baseline: 14.4389x; 1.5097x over previous
//
#include <hip/hip_runtime.h>
#include <hip/hip_bf16.h>

// Problem constants (Head_60421599920770): B=32, T=2048, C=256, HS=64
#define NB 32
#define NT 2048
#define NC 256
#define NH 64
#define QB 64
#define KB 64
#define MT 128   // qkv M-tile rows per block
#define KC 64    // qkv K-chunk

typedef __attribute__((ext_vector_type(8))) short bf16x8;   // 8 bf16 = 4 VGPRs
typedef __attribute__((ext_vector_type(4))) float f32x4;    // MFMA C/D

static constexpr float SCALE = 0.125f;   // HS^-0.5
static constexpr float LNEG  = -1e9f;

static __device__ inline short f2b(float x) {
    __hip_bfloat16 h = __float2bfloat16(x);
    return *reinterpret_cast<short*>(&h);
}
static __device__ inline float b2f(short s) {
    unsigned int u = ((unsigned int)(unsigned short)s) << 16;
    float f; __builtin_memcpy(&f, &u, 4); return f;
}

// ---------------------------------------------------------------------------
// W prep: Wt[n][k] bf16, n in [0,192): 0-63 Wq cols, 64-127 Wk, 128-191 Wv.
// Row n has contiguous k (0..255) -> direct MFMA fragment loads. 96KB, L2-res.
// ---------------------------------------------------------------------------
__global__ __launch_bounds__(256) void wprep_kernel(
    const float* __restrict__ Wq, const float* __restrict__ Wk,
    const float* __restrict__ Wv, __hip_bfloat16* __restrict__ Wt)
{
    const int n = blockIdx.x;            // 0..191
    const int k = threadIdx.x;           // 0..255
    const float* Wm = (n < 64) ? Wq : ((n < 128) ? Wk : Wv);
    Wt[n * NC + k] = __float2bfloat16(Wm[k * NH + (n & 63)]);
}

// ---------------------------------------------------------------------------
// QKV projection as bf16 MFMA GEMM. Block = 128 rows x all 192 outputs.
// Orientation: Q,K computed as D[n][t] (A=W,B=X) -> lane holds 4 consecutive n
// for fixed t -> short4 row-major stores. V computed as D[t][d] (A=X,B=W) ->
// lane holds 4 consecutive t for fixed d -> short4 stores into Vt[d][t].
// ---------------------------------------------------------------------------
__global__ __launch_bounds__(256, 2) void qkv_kernel(
    const float* __restrict__ X, const __hip_bfloat16* __restrict__ Wt,
    __hip_bfloat16* __restrict__ Q, __hip_bfloat16* __restrict__ K,
    __hip_bfloat16* __restrict__ Vt)
{
    __shared__ __hip_bfloat16 x_lds[MT][KC + 8];     // [128][72] rows t, k-chunk
    __shared__ __hip_bfloat16 w_lds[192][KC + 8];    // [192][72] rows n, k-chunk

    const int row0 = blockIdx.x * MT;    // flat row b*NT+t; 128|2048: no b cross
    const int tid  = threadIdx.x;
    const int wid  = tid >> 6;
    const int lane = tid & 63;
    const int l15  = lane & 15;
    const int lg   = lane >> 4;

    f32x4 aQ[4][2], aK[4][2], aV[2][4];
    #pragma unroll
    for (int i = 0; i < 4; ++i)
        #pragma unroll
        for (int j = 0; j < 2; ++j) {
            aQ[i][j] = (f32x4){0.f,0.f,0.f,0.f};
            aK[i][j] = (f32x4){0.f,0.f,0.f,0.f};
            aV[j][i] = (f32x4){0.f,0.f,0.f,0.f};
        }

    for (int kc = 0; kc < NC / KC; ++kc) {
        __syncthreads();                 // previous chunk fully consumed
        // stage X chunk (fp32 -> bf16), 16B LDS stores: 1024 units, 4 iters
        #pragma unroll
        for (int i = 0; i < 4; ++i) {
            int u = tid + i * 256;
            int r = u >> 3, c8 = (u & 7) * 8;
            const float* src = &X[(size_t)(row0 + r) * NC + kc * KC + c8];
            float4 f0 = *(const float4*)(src);
            float4 f1 = *(const float4*)(src + 4);
            bf16x8 o;
            o[0]=f2b(f0.x); o[1]=f2b(f0.y); o[2]=f2b(f0.z); o[3]=f2b(f0.w);
            o[4]=f2b(f1.x); o[5]=f2b(f1.y); o[6]=f2b(f1.z); o[7]=f2b(f1.w);
            *reinterpret_cast<bf16x8*>(&x_lds[r][c8]) = o;
        }
        // stage Wt chunk: 1536 units, 6 iters (L2-resident source)
        #pragma unroll
        for (int i = 0; i < 6; ++i) {
            int u = tid + i * 256;
            int r = u >> 3, c8 = (u & 7) * 8;
            *reinterpret_cast<bf16x8*>(&w_lds[r][c8]) =
                *reinterpret_cast<const bf16x8*>(&Wt[r * NC + kc * KC + c8]);
        }
        __syncthreads();

        #pragma unroll
        for (int ks = 0; ks < 2; ++ks) {
            bf16x8 xf[2];
            #pragma unroll
            for (int tf = 0; tf < 2; ++tf)
                xf[tf] = *reinterpret_cast<const bf16x8*>(
                    &x_lds[wid * 32 + tf * 16 + l15][ks * 32 + lg * 8]);
            #pragma unroll
            for (int nf = 0; nf < 4; ++nf) {
                bf16x8 wq = *reinterpret_cast<const bf16x8*>(
                    &w_lds[nf * 16 + l15][ks * 32 + lg * 8]);
                bf16x8 wk = *reinterpret_cast<const bf16x8*>(
                    &w_lds[64 + nf * 16 + l15][ks * 32 + lg * 8]);
                bf16x8 wv = *reinterpret_cast<const bf16x8*>(
                    &w_lds[128 + nf * 16 + l15][ks * 32 + lg * 8]);
                #pragma unroll
                for (int tf = 0; tf < 2; ++tf) {
                    aQ[nf][tf] = __builtin_amdgcn_mfma_f32_16x16x32_bf16(wq, xf[tf], aQ[nf][tf], 0, 0, 0);
                    aK[nf][tf] = __builtin_amdgcn_mfma_f32_16x16x32_bf16(wk, xf[tf], aK[nf][tf], 0, 0, 0);
                    aV[tf][nf] = __builtin_amdgcn_mfma_f32_16x16x32_bf16(xf[tf], wv, aV[tf][nf], 0, 0, 0);
                }
            }
        }
    }

    // epilogue: short4 stores
    const int b  = row0 >> 11;           // / NT
    const int t0 = row0 & (NT - 1);
    #pragma unroll
    for (int nf = 0; nf < 4; ++nf)
        #pragma unroll
        for (int tf = 0; tf < 2; ++tf) {
            size_t o = (size_t)(row0 + wid * 32 + tf * 16 + l15) * NH + nf * 16 + lg * 4;
            short4 sq, sk;
            sq.x = f2b(aQ[nf][tf][0]); sq.y = f2b(aQ[nf][tf][1]);
            sq.z = f2b(aQ[nf][tf][2]); sq.w = f2b(aQ[nf][tf][3]);
            sk.x = f2b(aK[nf][tf][0]); sk.y = f2b(aK[nf][tf][1]);
            sk.z = f2b(aK[nf][tf][2]); sk.w = f2b(aK[nf][tf][3]);
            *reinterpret_cast<short4*>(&Q[o]) = sq;
            *reinterpret_cast<short4*>(&K[o]) = sk;
        }
    #pragma unroll
    for (int tf = 0; tf < 2; ++tf)
        #pragma unroll
        for (int df = 0; df < 4; ++df) {
            int d  = df * 16 + l15;
            int t4 = t0 + wid * 32 + tf * 16 + lg * 4;
            short4 sv;
            sv.x = f2b(aV[tf][df][0]); sv.y = f2b(aV[tf][df][1]);
            sv.z = f2b(aV[tf][df][2]); sv.w = f2b(aV[tf][df][3]);
            *reinterpret_cast<short4*>(&Vt[((size_t)b * NH + d) * NT + t4]) = sv;
        }
}

// ---------------------------------------------------------------------------
// Kernel B: mean over all T of V (per batch, per d) from transposed Vt.
// Needed for fully-masked causal rows (reference softmax -> uniform over ALL keys).
// ---------------------------------------------------------------------------
__global__ __launch_bounds__(1024) void meanv_kernel(
    const __hip_bfloat16* __restrict__ Vt, float* __restrict__ MV)
{
    __shared__ float red[NH][17];
    const int b    = blockIdx.x;
    const int tid  = threadIdx.x;
    const int d    = tid >> 4;
    const int part = tid & 15;
    const __hip_bfloat16* row = Vt + ((size_t)b * NH + d) * NT;
    float s = 0.f;
    for (int t = part * 128; t < part * 128 + 128; t += 8) {
        bf16x8 v = *reinterpret_cast<const bf16x8*>(&row[t]);
        #pragma unroll
        for (int j = 0; j < 8; ++j) s += b2f(v[j]);
    }
    red[d][part] = s;
    __syncthreads();
    if (part == 0) {
        float tot = 0.f;
        #pragma unroll
        for (int i = 0; i < 16; ++i) tot += red[d][i];
        MV[b * NH + d] = tot * (1.0f / NT);
    }
}

// ---------------------------------------------------------------------------
// Kernel C: bf16 MFMA flash attention (16x16x32), causal + padding mask.
// (verified round 1; unchanged)
// ---------------------------------------------------------------------------
__global__ __launch_bounds__(256) void attn_kernel(
    const __hip_bfloat16* __restrict__ Q, const __hip_bfloat16* __restrict__ K,
    const __hip_bfloat16* __restrict__ Vt, const int* __restrict__ mask,
    const float* __restrict__ MV, float* __restrict__ Out)
{
    __shared__ __hip_bfloat16 k_lds[KB][NH + 8];       // [64][72] keys row-major
    __shared__ __hip_bfloat16 vt_lds[NH][KB + 8];      // [64][72] V transposed (d, k)
    __shared__ __hip_bfloat16 p_lds[4][16][KB + 8];    // per-wave P (16 q x 64 k)

    const int bq  = blockIdx.x;
    const int b   = bq >> 5;               // 32 q-groups per batch
    const int idx = bq & 31;
    const int qg  = (idx & 1) ? (31 - (idx >> 1)) : (idx >> 1);
    const int q0  = qg * QB;
    const int tid = threadIdx.x;
    const int wid = tid >> 6;
    const int lane = tid & 63;
    const int l15 = lane & 15;
    const int lg  = lane >> 4;

    const __hip_bfloat16* Kg = K  + (size_t)b * NT * NH;
    const __hip_bfloat16* Vg = Vt + (size_t)b * NH * NT;
    const int* Mb = mask + b * NT;

    const int qrow_blk = q0 + wid * 16;
    bf16x8 qf0, qf1;
    {
        const __hip_bfloat16* Qr = Q + ((size_t)b * NT + qrow_blk + l15) * NH;
        qf0 = *reinterpret_cast<const bf16x8*>(&Qr[lg * 8]);
        qf1 = *reinterpret_cast<const bf16x8*>(&Qr[lg * 8 + 32]);
    }

    f32x4 o_acc[4];
    float m_r[4], l_r[4];
    #pragma unroll
    for (int dt = 0; dt < 4; ++dt) o_acc[dt] = (f32x4){0.f,0.f,0.f,0.f};
    #pragma unroll
    for (int r = 0; r < 4; ++r) { m_r[r] = -3.0e38f; l_r[r] = 0.f; }

    const int qbase = qrow_blk + lg * 4;

    const int ntiles = qg + 1;
    for (int kt = 0; kt < ntiles; ++kt) {
        const int k0 = kt * KB;
        __syncthreads();
        #pragma unroll
        for (int i = 0; i < 2; ++i) {
            int e = tid + i * 256;
            int r = e >> 3, c = (e & 7) * 8;
            *reinterpret_cast<bf16x8*>(&k_lds[r][c]) =
                *reinterpret_cast<const bf16x8*>(&Kg[(size_t)(k0 + r) * NH + c]);
            *reinterpret_cast<bf16x8*>(&vt_lds[r][c]) =
                *reinterpret_cast<const bf16x8*>(&Vg[(size_t)r * NT + k0 + c]);
        }
        __syncthreads();

        f32x4 s[4];
        #pragma unroll
        for (int jt = 0; jt < 4; ++jt) s[jt] = (f32x4){0.f,0.f,0.f,0.f};
        #pragma unroll
        for (int jt = 0; jt < 4; ++jt) {
            bf16x8 kfa = *reinterpret_cast<const bf16x8*>(&k_lds[jt*16 + l15][lg*8]);
            bf16x8 kfb = *reinterpret_cast<const bf16x8*>(&k_lds[jt*16 + l15][lg*8 + 32]);
            s[jt] = __builtin_amdgcn_mfma_f32_16x16x32_bf16(qf0, kfa, s[jt], 0, 0, 0);
            s[jt] = __builtin_amdgcn_mfma_f32_16x16x32_bf16(qf1, kfb, s[jt], 0, 0, 0);
        }

        int mv[4];
        #pragma unroll
        for (int jt = 0; jt < 4; ++jt) mv[jt] = Mb[k0 + jt*16 + l15];

        float sm[4][4];
        #pragma unroll
        for (int jt = 0; jt < 4; ++jt) {
            const int key = k0 + jt * 16 + l15;
            const bool mz = (mv[jt] == 0);
            #pragma unroll
            for (int r = 0; r < 4; ++r) {
                float v = s[jt][r] * SCALE;
                if (key > qbase + r || mz) v = LNEG;
                sm[jt][r] = v;
            }
        }
        #pragma unroll
        for (int r = 0; r < 4; ++r) {
            float tm = fmaxf(fmaxf(sm[0][r], sm[1][r]), fmaxf(sm[2][r], sm[3][r]));
            #pragma unroll
            for (int off = 1; off < 16; off <<= 1) tm = fmaxf(tm, __shfl_xor(tm, off));
            const float mnew = fmaxf(m_r[r], tm);
            const float al   = __expf(m_r[r] - mnew);
            m_r[r] = mnew;
            float rs = 0.f;
            #pragma unroll
            for (int jt = 0; jt < 4; ++jt) {
                float pv = __expf(sm[jt][r] - mnew);
                p_lds[wid][lg * 4 + r][jt * 16 + l15] = __float2bfloat16(pv);
                rs += pv;
            }
            #pragma unroll
            for (int off = 1; off < 16; off <<= 1) rs += __shfl_xor(rs, off);
            l_r[r] = l_r[r] * al + rs;
            #pragma unroll
            for (int dt = 0; dt < 4; ++dt) o_acc[dt][r] *= al;
        }

        bf16x8 pa0 = *reinterpret_cast<const bf16x8*>(&p_lds[wid][l15][lg * 8]);
        bf16x8 pa1 = *reinterpret_cast<const bf16x8*>(&p_lds[wid][l15][lg * 8 + 32]);
        #pragma unroll
        for (int dt = 0; dt < 4; ++dt) {
            bf16x8 vfa = *reinterpret_cast<const bf16x8*>(&vt_lds[dt*16 + l15][lg*8]);
            bf16x8 vfb = *reinterpret_cast<const bf16x8*>(&vt_lds[dt*16 + l15][lg*8 + 32]);
            o_acc[dt] = __builtin_amdgcn_mfma_f32_16x16x32_bf16(pa0, vfa, o_acc[dt], 0, 0, 0);
            o_acc[dt] = __builtin_amdgcn_mfma_f32_16x16x32_bf16(pa1, vfb, o_acc[dt], 0, 0, 0);
        }
    }

    float* Ob = Out + (size_t)b * NT * NH;
    #pragma unroll
    for (int r = 0; r < 4; ++r) {
        const int  qrow  = qbase + r;
        const bool degen = (m_r[r] <= -5.0e8f);
        const float inv  = degen ? 0.f : 1.0f / l_r[r];
        #pragma unroll
        for (int dt = 0; dt < 4; ++dt) {
            const int d = dt * 16 + l15;
            float val = degen ? MV[b * NH + d] : o_acc[dt][r] * inv;
            Ob[(size_t)qrow * NH + d] = val;
        }
    }
}

// ---------------------------------------------------------------------------
extern "C" void kernel_launch(void* const* d_in, const int* in_sizes, int n_in,
                              void* d_out, int out_size, void* d_ws, size_t ws_size,
                              hipStream_t stream)
{
    const float* X  = (const float*)d_in[0];   // q_input (B,T,C) fp32
    const float* Wq = (const float*)d_in[1];
    const float* Wk = (const float*)d_in[2];
    const float* Wv = (const float*)d_in[3];
    const int*   M  = (const int*)d_in[4];     // attn_mask (B,T) int32
    float* out = (float*)d_out;                // (B,T,HS) fp32

    // workspace: Q,K,Vt bf16 (8MB each) + MV f32 (8KB) + Wt bf16 (96KB)
    __hip_bfloat16* Qp = (__hip_bfloat16*)d_ws;
    __hip_bfloat16* Kp = Qp + (size_t)NB * NT * NH;
    __hip_bfloat16* Vp = Kp + (size_t)NB * NT * NH;
    float* MVp = (float*)(Vp + (size_t)NB * NT * NH);
    __hip_bfloat16* Wtp = (__hip_bfloat16*)(MVp + NB * NH);

    wprep_kernel<<<192, 256, 0, stream>>>(Wq, Wk, Wv, Wtp);
    qkv_kernel<<<NB * NT / MT, 256, 0, stream>>>(X, Wtp, Qp, Kp, Vp);
    meanv_kernel<<<NB, 1024, 0, stream>>>(Vp, MVp);
    attn_kernel<<<NB * NT / QB, 256, 0, stream>>>(Qp, Kp, Vp, M, MVp, out);
}

// Round 4
// 119.891 us; speedup vs baseline: 19.9219x; 1.3797x over previous
//
#include <hip/hip_runtime.h>
#include <hip/hip_bf16.h>

// Problem constants (Head_60421599920770): B=32, T=2048, C=256, HS=64
#define NB 32
#define NT 2048
#define NC 256
#define NH 64
#define QB 64
#define KB 64
#define MT 128   // qkv M-tile rows per block
#define KC 64    // qkv K-chunk

typedef __attribute__((ext_vector_type(8))) short bf16x8;   // 8 bf16 = 4 VGPRs
typedef __attribute__((ext_vector_type(4))) float f32x4;    // MFMA C/D

static constexpr float SCALE = 0.125f;   // HS^-0.5
static constexpr float LNEG  = -1e9f;

static __device__ inline short f2b(float x) {
    __hip_bfloat16 h = __float2bfloat16(x);
    return *reinterpret_cast<short*>(&h);
}
static __device__ inline float b2f(short s) {
    unsigned int u = ((unsigned int)(unsigned short)s) << 16;
    float f; __builtin_memcpy(&f, &u, 4); return f;
}

// ---------------------------------------------------------------------------
// W prep: Wt[n][k] bf16, n in [0,192): 0-63 Wq cols, 64-127 Wk, 128-191 Wv.
// ---------------------------------------------------------------------------
__global__ __launch_bounds__(256) void wprep_kernel(
    const float* __restrict__ Wq, const float* __restrict__ Wk,
    const float* __restrict__ Wv, __hip_bfloat16* __restrict__ Wt)
{
    const int n = blockIdx.x;            // 0..191
    const int k = threadIdx.x;           // 0..255
    const float* Wm = (n < 64) ? Wq : ((n < 128) ? Wk : Wv);
    Wt[n * NC + k] = __float2bfloat16(Wm[k * NH + (n & 63)]);
}

// ---------------------------------------------------------------------------
// QKV projection as bf16 MFMA GEMM (verified round 2; unchanged).
// ---------------------------------------------------------------------------
__global__ __launch_bounds__(256, 2) void qkv_kernel(
    const float* __restrict__ X, const __hip_bfloat16* __restrict__ Wt,
    __hip_bfloat16* __restrict__ Q, __hip_bfloat16* __restrict__ K,
    __hip_bfloat16* __restrict__ Vt)
{
    __shared__ __hip_bfloat16 x_lds[MT][KC + 8];
    __shared__ __hip_bfloat16 w_lds[192][KC + 8];

    const int row0 = blockIdx.x * MT;
    const int tid  = threadIdx.x;
    const int wid  = tid >> 6;
    const int lane = tid & 63;
    const int l15  = lane & 15;
    const int lg   = lane >> 4;

    f32x4 aQ[4][2], aK[4][2], aV[2][4];
    #pragma unroll
    for (int i = 0; i < 4; ++i)
        #pragma unroll
        for (int j = 0; j < 2; ++j) {
            aQ[i][j] = (f32x4){0.f,0.f,0.f,0.f};
            aK[i][j] = (f32x4){0.f,0.f,0.f,0.f};
            aV[j][i] = (f32x4){0.f,0.f,0.f,0.f};
        }

    for (int kc = 0; kc < NC / KC; ++kc) {
        __syncthreads();
        #pragma unroll
        for (int i = 0; i < 4; ++i) {
            int u = tid + i * 256;
            int r = u >> 3, c8 = (u & 7) * 8;
            const float* src = &X[(size_t)(row0 + r) * NC + kc * KC + c8];
            float4 f0 = *(const float4*)(src);
            float4 f1 = *(const float4*)(src + 4);
            bf16x8 o;
            o[0]=f2b(f0.x); o[1]=f2b(f0.y); o[2]=f2b(f0.z); o[3]=f2b(f0.w);
            o[4]=f2b(f1.x); o[5]=f2b(f1.y); o[6]=f2b(f1.z); o[7]=f2b(f1.w);
            *reinterpret_cast<bf16x8*>(&x_lds[r][c8]) = o;
        }
        #pragma unroll
        for (int i = 0; i < 6; ++i) {
            int u = tid + i * 256;
            int r = u >> 3, c8 = (u & 7) * 8;
            *reinterpret_cast<bf16x8*>(&w_lds[r][c8]) =
                *reinterpret_cast<const bf16x8*>(&Wt[r * NC + kc * KC + c8]);
        }
        __syncthreads();

        #pragma unroll
        for (int ks = 0; ks < 2; ++ks) {
            bf16x8 xf[2];
            #pragma unroll
            for (int tf = 0; tf < 2; ++tf)
                xf[tf] = *reinterpret_cast<const bf16x8*>(
                    &x_lds[wid * 32 + tf * 16 + l15][ks * 32 + lg * 8]);
            #pragma unroll
            for (int nf = 0; nf < 4; ++nf) {
                bf16x8 wq = *reinterpret_cast<const bf16x8*>(
                    &w_lds[nf * 16 + l15][ks * 32 + lg * 8]);
                bf16x8 wk = *reinterpret_cast<const bf16x8*>(
                    &w_lds[64 + nf * 16 + l15][ks * 32 + lg * 8]);
                bf16x8 wv = *reinterpret_cast<const bf16x8*>(
                    &w_lds[128 + nf * 16 + l15][ks * 32 + lg * 8]);
                #pragma unroll
                for (int tf = 0; tf < 2; ++tf) {
                    aQ[nf][tf] = __builtin_amdgcn_mfma_f32_16x16x32_bf16(wq, xf[tf], aQ[nf][tf], 0, 0, 0);
                    aK[nf][tf] = __builtin_amdgcn_mfma_f32_16x16x32_bf16(wk, xf[tf], aK[nf][tf], 0, 0, 0);
                    aV[tf][nf] = __builtin_amdgcn_mfma_f32_16x16x32_bf16(xf[tf], wv, aV[tf][nf], 0, 0, 0);
                }
            }
        }
    }

    const int b  = row0 >> 11;
    const int t0 = row0 & (NT - 1);
    #pragma unroll
    for (int nf = 0; nf < 4; ++nf)
        #pragma unroll
        for (int tf = 0; tf < 2; ++tf) {
            size_t o = (size_t)(row0 + wid * 32 + tf * 16 + l15) * NH + nf * 16 + lg * 4;
            short4 sq, sk;
            sq.x = f2b(aQ[nf][tf][0]); sq.y = f2b(aQ[nf][tf][1]);
            sq.z = f2b(aQ[nf][tf][2]); sq.w = f2b(aQ[nf][tf][3]);
            sk.x = f2b(aK[nf][tf][0]); sk.y = f2b(aK[nf][tf][1]);
            sk.z = f2b(aK[nf][tf][2]); sk.w = f2b(aK[nf][tf][3]);
            *reinterpret_cast<short4*>(&Q[o]) = sq;
            *reinterpret_cast<short4*>(&K[o]) = sk;
        }
    #pragma unroll
    for (int tf = 0; tf < 2; ++tf)
        #pragma unroll
        for (int df = 0; df < 4; ++df) {
            int d  = df * 16 + l15;
            int t4 = t0 + wid * 32 + tf * 16 + lg * 4;
            short4 sv;
            sv.x = f2b(aV[tf][df][0]); sv.y = f2b(aV[tf][df][1]);
            sv.z = f2b(aV[tf][df][2]); sv.w = f2b(aV[tf][df][3]);
            *reinterpret_cast<short4*>(&Vt[((size_t)b * NH + d) * NT + t4]) = sv;
        }
}

// ---------------------------------------------------------------------------
// Kernel B: mean over T of V per (batch, d) — degenerate-row fixup source.
// ---------------------------------------------------------------------------
__global__ __launch_bounds__(1024) void meanv_kernel(
    const __hip_bfloat16* __restrict__ Vt, float* __restrict__ MV)
{
    __shared__ float red[NH][17];
    const int b    = blockIdx.x;
    const int tid  = threadIdx.x;
    const int d    = tid >> 4;
    const int part = tid & 15;
    const __hip_bfloat16* row = Vt + ((size_t)b * NH + d) * NT;
    float s = 0.f;
    for (int t = part * 128; t < part * 128 + 128; t += 8) {
        bf16x8 v = *reinterpret_cast<const bf16x8*>(&row[t]);
        #pragma unroll
        for (int j = 0; j < 8; ++j) s += b2f(v[j]);
    }
    red[d][part] = s;
    __syncthreads();
    if (part == 0) {
        float tot = 0.f;
        #pragma unroll
        for (int i = 0; i < 16; ++i) tot += red[d][i];
        MV[b * NH + d] = tot * (1.0f / NT);
    }
}

// ---------------------------------------------------------------------------
// Kernel C: swapped-operand bf16 MFMA flash attention.
// QK^T = mfma(K, Q) -> D[key][q]: lane owns query l15, 16 keys.
// Key->tile map chosen so lane's held keys == its PV B-fragment keys:
//   key(jt, i) = ((jt&2)<<4) | ((i>>2)<<3) | ((jt&1)<<2) | (i&3),  i = row idx.
// PV = mfma(V^T, P^T): P stays in registers (8 packs, no LDS, no shuffles).
// Softmax: 15 lane-local fmax/add + 2 shfl_xor (16,32) per reduction.
// K LDS rows permuted by sig(k)=(k&56)|((k+2*(k>>3))&7) for 2-way banking.
// ---------------------------------------------------------------------------
__global__ __launch_bounds__(256) void attn_kernel(
    const __hip_bfloat16* __restrict__ Q, const __hip_bfloat16* __restrict__ K,
    const __hip_bfloat16* __restrict__ Vt, const int* __restrict__ mask,
    const float* __restrict__ MV, float* __restrict__ Out)
{
    __shared__ __hip_bfloat16 k_lds[KB][NH + 8];   // row sig(key), col d
    __shared__ __hip_bfloat16 vt_lds[NH][KB + 8];  // row d, col key

    const int bq  = blockIdx.x;
    const int b   = bq >> 5;
    const int idx = bq & 31;
    const int qg  = (idx & 1) ? (31 - (idx >> 1)) : (idx >> 1);
    const int q0  = qg * QB;
    const int tid = threadIdx.x;
    const int wid = tid >> 6;
    const int lane = tid & 63;
    const int l15 = lane & 15;
    const int lg  = lane >> 4;

    const __hip_bfloat16* Kg = K  + (size_t)b * NT * NH;
    const __hip_bfloat16* Vg = Vt + (size_t)b * NH * NT;
    const int* Mb = mask + b * NT;

    const int q = q0 + wid * 16 + l15;             // this lane's query row
    bf16x8 qf0, qf1;
    {
        const __hip_bfloat16* Qr = Q + ((size_t)b * NT + q) * NH;
        qf0 = *reinterpret_cast<const bf16x8*>(&Qr[lg * 8]);
        qf1 = *reinterpret_cast<const bf16x8*>(&Qr[lg * 8 + 32]);
    }

    f32x4 o_acc[4];
    #pragma unroll
    for (int dt = 0; dt < 4; ++dt) o_acc[dt] = (f32x4){0.f,0.f,0.f,0.f};
    float m_r = -3.0e38f, l_r = 0.f;

    // K-fragment LDS rows (sigma'd) and key offsets per jt
    int krow[4], koff[4];
    #pragma unroll
    for (int jt = 0; jt < 4; ++jt) {
        int kr  = ((jt & 2) << 4) | ((l15 >> 2) << 3) | ((jt & 1) << 2) | (l15 & 3);
        krow[jt] = (kr & 56) | ((kr + 2 * (kr >> 3)) & 7);
        koff[jt] = ((jt & 2) << 4) | (lg << 3) | ((jt & 1) << 2);
    }

    // staging coords: thread writes rows sr, sr+32; 16B chunk sc
    const int sr  = tid >> 3;            // 0..31
    const int sc  = (tid & 7) * 8;
    const int sg0 = (sr & 56) | ((sr + 2 * (sr >> 3)) & 7);           // sig(sr)
    const int sg1 = ((sr+32) & 56) | (((sr+32) + 2 * ((sr+32) >> 3)) & 7);

    // prefetch tile 0
    bf16x8 kp0 = *reinterpret_cast<const bf16x8*>(&Kg[(size_t)sr * NH + sc]);
    bf16x8 kp1 = *reinterpret_cast<const bf16x8*>(&Kg[(size_t)(sr + 32) * NH + sc]);
    bf16x8 vp0 = *reinterpret_cast<const bf16x8*>(&Vg[(size_t)sr * NT + sc]);
    bf16x8 vp1 = *reinterpret_cast<const bf16x8*>(&Vg[(size_t)(sr + 32) * NT + sc]);

    for (int kt = 0; kt <= qg; ++kt) {
        const int k0 = kt * KB;
        __syncthreads();                   // previous tile fully consumed
        *reinterpret_cast<bf16x8*>(&k_lds[sg0][sc]) = kp0;
        *reinterpret_cast<bf16x8*>(&k_lds[sg1][sc]) = kp1;
        *reinterpret_cast<bf16x8*>(&vt_lds[sr][sc]) = vp0;
        *reinterpret_cast<bf16x8*>(&vt_lds[sr + 32][sc]) = vp1;
        __syncthreads();

        if (kt < qg) {                     // prefetch next tile (overlaps compute)
            const int kn = k0 + KB;
            kp0 = *reinterpret_cast<const bf16x8*>(&Kg[(size_t)(kn + sr) * NH + sc]);
            kp1 = *reinterpret_cast<const bf16x8*>(&Kg[(size_t)(kn + sr + 32) * NH + sc]);
            vp0 = *reinterpret_cast<const bf16x8*>(&Vg[(size_t)sr * NT + kn + sc]);
            vp1 = *reinterpret_cast<const bf16x8*>(&Vg[(size_t)(sr + 32) * NT + kn + sc]);
        }

        // ---- QK^T (swapped): s[jt] = D[key-tile jt][q] ----
        f32x4 s[4];
        #pragma unroll
        for (int jt = 0; jt < 4; ++jt) {
            s[jt] = (f32x4){0.f,0.f,0.f,0.f};
            bf16x8 kfa = *reinterpret_cast<const bf16x8*>(&k_lds[krow[jt]][lg * 8]);
            bf16x8 kfb = *reinterpret_cast<const bf16x8*>(&k_lds[krow[jt]][lg * 8 + 32]);
            s[jt] = __builtin_amdgcn_mfma_f32_16x16x32_bf16(kfa, qf0, s[jt], 0, 0, 0);
            s[jt] = __builtin_amdgcn_mfma_f32_16x16x32_bf16(kfb, qf1, s[jt], 0, 0, 0);
        }

        // ---- mask + scale (lane-local: 16 scores for query q) ----
        float sm[4][4];
        #pragma unroll
        for (int jt = 0; jt < 4; ++jt) {
            int4 mv = *reinterpret_cast<const int4*>(&Mb[k0 + koff[jt]]);
            const int kb = k0 + koff[jt];
            sm[jt][0] = (kb + 0 > q || mv.x == 0) ? LNEG : s[jt][0] * SCALE;
            sm[jt][1] = (kb + 1 > q || mv.y == 0) ? LNEG : s[jt][1] * SCALE;
            sm[jt][2] = (kb + 2 > q || mv.z == 0) ? LNEG : s[jt][2] * SCALE;
            sm[jt][3] = (kb + 3 > q || mv.w == 0) ? LNEG : s[jt][3] * SCALE;
        }

        // ---- online softmax: lane-local tree + 2 cross-lane steps ----
        float tm = sm[0][0];
        #pragma unroll
        for (int jt = 0; jt < 4; ++jt)
            #pragma unroll
            for (int r = 0; r < 4; ++r) tm = fmaxf(tm, sm[jt][r]);
        tm = fmaxf(tm, __shfl_xor(tm, 16));
        tm = fmaxf(tm, __shfl_xor(tm, 32));
        const float mnew = fmaxf(m_r, tm);
        const float al   = __expf(m_r - mnew);
        m_r = mnew;

        float p[4][4], rs = 0.f;
        #pragma unroll
        for (int jt = 0; jt < 4; ++jt)
            #pragma unroll
            for (int r = 0; r < 4; ++r) {
                p[jt][r] = __expf(sm[jt][r] - mnew);
                rs += p[jt][r];
            }
        rs += __shfl_xor(rs, 16);
        rs += __shfl_xor(rs, 32);
        l_r = l_r * al + rs;

        // ---- P -> bf16 B-fragments, all in-register ----
        bf16x8 pb0, pb1;
        #pragma unroll
        for (int r = 0; r < 4; ++r) {
            pb0[r]     = f2b(p[0][r]);   // keys lg*8 + r
            pb0[4 + r] = f2b(p[1][r]);   // keys lg*8 + 4 + r
            pb1[r]     = f2b(p[2][r]);   // keys 32 + lg*8 + r
            pb1[4 + r] = f2b(p[3][r]);   // keys 32 + lg*8 + 4 + r
        }

        // ---- PV (swapped): o_acc[dt] += V^T x P^T ----
        #pragma unroll
        for (int dt = 0; dt < 4; ++dt) {
            #pragma unroll
            for (int r = 0; r < 4; ++r) o_acc[dt][r] *= al;
            bf16x8 vfa = *reinterpret_cast<const bf16x8*>(&vt_lds[dt*16 + l15][lg*8]);
            bf16x8 vfb = *reinterpret_cast<const bf16x8*>(&vt_lds[dt*16 + l15][lg*8 + 32]);
            o_acc[dt] = __builtin_amdgcn_mfma_f32_16x16x32_bf16(vfa, pb0, o_acc[dt], 0, 0, 0);
            o_acc[dt] = __builtin_amdgcn_mfma_f32_16x16x32_bf16(vfb, pb1, o_acc[dt], 0, 0, 0);
        }
    }

    // ---- epilogue: float4 stores; degenerate rows -> mean V ----
    const bool degen = (m_r <= -5.0e8f);
    const float inv  = degen ? 0.f : 1.0f / l_r;
    float* Or = Out + ((size_t)b * NT + q) * NH;
    #pragma unroll
    for (int dt = 0; dt < 4; ++dt) {
        float4 o;
        if (degen) {
            o = *reinterpret_cast<const float4*>(&MV[b * NH + dt * 16 + lg * 4]);
        } else {
            o.x = o_acc[dt][0] * inv; o.y = o_acc[dt][1] * inv;
            o.z = o_acc[dt][2] * inv; o.w = o_acc[dt][3] * inv;
        }
        *reinterpret_cast<float4*>(&Or[dt * 16 + lg * 4]) = o;
    }
}

// ---------------------------------------------------------------------------
extern "C" void kernel_launch(void* const* d_in, const int* in_sizes, int n_in,
                              void* d_out, int out_size, void* d_ws, size_t ws_size,
                              hipStream_t stream)
{
    const float* X  = (const float*)d_in[0];   // q_input (B,T,C) fp32
    const float* Wq = (const float*)d_in[1];
    const float* Wk = (const float*)d_in[2];
    const float* Wv = (const float*)d_in[3];
    const int*   M  = (const int*)d_in[4];     // attn_mask (B,T) int32
    float* out = (float*)d_out;                // (B,T,HS) fp32

    __hip_bfloat16* Qp = (__hip_bfloat16*)d_ws;
    __hip_bfloat16* Kp = Qp + (size_t)NB * NT * NH;
    __hip_bfloat16* Vp = Kp + (size_t)NB * NT * NH;
    float* MVp = (float*)(Vp + (size_t)NB * NT * NH);
    __hip_bfloat16* Wtp = (__hip_bfloat16*)(MVp + NB * NH);

    wprep_kernel<<<192, 256, 0, stream>>>(Wq, Wk, Wv, Wtp);
    qkv_kernel<<<NB * NT / MT, 256, 0, stream>>>(X, Wtp, Qp, Kp, Vp);
    meanv_kernel<<<NB, 1024, 0, stream>>>(Vp, MVp);
    attn_kernel<<<NB * NT / QB, 256, 0, stream>>>(Qp, Kp, Vp, M, MVp, out);
}

// Round 5
// 100.146 us; speedup vs baseline: 23.8498x; 1.1972x over previous
//
#include <hip/hip_runtime.h>
#include <hip/hip_bf16.h>

// Problem constants (Head_60421599920770): B=32, T=2048, C=256, HS=64
#define NB 32
#define NT 2048
#define NC 256
#define NH 64
#define QB 64
#define KB 64
#define MT 128   // qkv M-tile rows per block
#define KC 64    // qkv K-chunk

typedef __attribute__((ext_vector_type(8))) short bf16x8;   // 8 bf16 = 4 VGPRs
typedef __attribute__((ext_vector_type(4))) float f32x4;    // MFMA C/D

static constexpr float SCALE2 = 0.18033688011112042f;  // HS^-0.5 * log2(e)
static constexpr float LNEG   = -1e9f;

static __device__ inline short f2b(float x) {
    __hip_bfloat16 h = __float2bfloat16(x);
    return *reinterpret_cast<short*>(&h);
}
static __device__ inline float b2f(short s) {
    unsigned int u = ((unsigned int)(unsigned short)s) << 16;
    float f; __builtin_memcpy(&f, &u, 4); return f;
}

// ---------------------------------------------------------------------------
// W prep: Wt[n][k] bf16, n in [0,192): 0-63 Wq cols, 64-127 Wk, 128-191 Wv.
// ---------------------------------------------------------------------------
__global__ __launch_bounds__(256) void wprep_kernel(
    const float* __restrict__ Wq, const float* __restrict__ Wk,
    const float* __restrict__ Wv, __hip_bfloat16* __restrict__ Wt)
{
    const int n = blockIdx.x;            // 0..191
    const int k = threadIdx.x;           // 0..255
    const float* Wm = (n < 64) ? Wq : ((n < 128) ? Wk : Wv);
    Wt[n * NC + k] = __float2bfloat16(Wm[k * NH + (n & 63)]);
}

// ---------------------------------------------------------------------------
// Bias prep: Bias[b][t] = mask ? 0 : -1e9 (folded into QK MFMA accumulator).
// ---------------------------------------------------------------------------
__global__ __launch_bounds__(256) void biasprep_kernel(
    const int* __restrict__ M, float* __restrict__ Bias)
{
    const int i = blockIdx.x * 256 + threadIdx.x;
    Bias[i] = M[i] ? 0.f : LNEG;
}

// ---------------------------------------------------------------------------
// QKV projection as bf16 MFMA GEMM (verified round 2).
// Q is PRE-SCALED by HS^-0.5*log2(e) so attention softmax runs in exp2 domain.
// ---------------------------------------------------------------------------
__global__ __launch_bounds__(256, 2) void qkv_kernel(
    const float* __restrict__ X, const __hip_bfloat16* __restrict__ Wt,
    __hip_bfloat16* __restrict__ Q, __hip_bfloat16* __restrict__ K,
    __hip_bfloat16* __restrict__ Vt)
{
    __shared__ __hip_bfloat16 x_lds[MT][KC + 8];
    __shared__ __hip_bfloat16 w_lds[192][KC + 8];

    const int row0 = blockIdx.x * MT;
    const int tid  = threadIdx.x;
    const int wid  = tid >> 6;
    const int lane = tid & 63;
    const int l15  = lane & 15;
    const int lg   = lane >> 4;

    f32x4 aQ[4][2], aK[4][2], aV[2][4];
    #pragma unroll
    for (int i = 0; i < 4; ++i)
        #pragma unroll
        for (int j = 0; j < 2; ++j) {
            aQ[i][j] = (f32x4){0.f,0.f,0.f,0.f};
            aK[i][j] = (f32x4){0.f,0.f,0.f,0.f};
            aV[j][i] = (f32x4){0.f,0.f,0.f,0.f};
        }

    for (int kc = 0; kc < NC / KC; ++kc) {
        __syncthreads();
        #pragma unroll
        for (int i = 0; i < 4; ++i) {
            int u = tid + i * 256;
            int r = u >> 3, c8 = (u & 7) * 8;
            const float* src = &X[(size_t)(row0 + r) * NC + kc * KC + c8];
            float4 f0 = *(const float4*)(src);
            float4 f1 = *(const float4*)(src + 4);
            bf16x8 o;
            o[0]=f2b(f0.x); o[1]=f2b(f0.y); o[2]=f2b(f0.z); o[3]=f2b(f0.w);
            o[4]=f2b(f1.x); o[5]=f2b(f1.y); o[6]=f2b(f1.z); o[7]=f2b(f1.w);
            *reinterpret_cast<bf16x8*>(&x_lds[r][c8]) = o;
        }
        #pragma unroll
        for (int i = 0; i < 6; ++i) {
            int u = tid + i * 256;
            int r = u >> 3, c8 = (u & 7) * 8;
            *reinterpret_cast<bf16x8*>(&w_lds[r][c8]) =
                *reinterpret_cast<const bf16x8*>(&Wt[r * NC + kc * KC + c8]);
        }
        __syncthreads();

        #pragma unroll
        for (int ks = 0; ks < 2; ++ks) {
            bf16x8 xf[2];
            #pragma unroll
            for (int tf = 0; tf < 2; ++tf)
                xf[tf] = *reinterpret_cast<const bf16x8*>(
                    &x_lds[wid * 32 + tf * 16 + l15][ks * 32 + lg * 8]);
            #pragma unroll
            for (int nf = 0; nf < 4; ++nf) {
                bf16x8 wq = *reinterpret_cast<const bf16x8*>(
                    &w_lds[nf * 16 + l15][ks * 32 + lg * 8]);
                bf16x8 wk = *reinterpret_cast<const bf16x8*>(
                    &w_lds[64 + nf * 16 + l15][ks * 32 + lg * 8]);
                bf16x8 wv = *reinterpret_cast<const bf16x8*>(
                    &w_lds[128 + nf * 16 + l15][ks * 32 + lg * 8]);
                #pragma unroll
                for (int tf = 0; tf < 2; ++tf) {
                    aQ[nf][tf] = __builtin_amdgcn_mfma_f32_16x16x32_bf16(wq, xf[tf], aQ[nf][tf], 0, 0, 0);
                    aK[nf][tf] = __builtin_amdgcn_mfma_f32_16x16x32_bf16(wk, xf[tf], aK[nf][tf], 0, 0, 0);
                    aV[tf][nf] = __builtin_amdgcn_mfma_f32_16x16x32_bf16(xf[tf], wv, aV[tf][nf], 0, 0, 0);
                }
            }
        }
    }

    const int b  = row0 >> 11;
    const int t0 = row0 & (NT - 1);
    #pragma unroll
    for (int nf = 0; nf < 4; ++nf)
        #pragma unroll
        for (int tf = 0; tf < 2; ++tf) {
            size_t o = (size_t)(row0 + wid * 32 + tf * 16 + l15) * NH + nf * 16 + lg * 4;
            short4 sq, sk;
            sq.x = f2b(aQ[nf][tf][0] * SCALE2); sq.y = f2b(aQ[nf][tf][1] * SCALE2);
            sq.z = f2b(aQ[nf][tf][2] * SCALE2); sq.w = f2b(aQ[nf][tf][3] * SCALE2);
            sk.x = f2b(aK[nf][tf][0]); sk.y = f2b(aK[nf][tf][1]);
            sk.z = f2b(aK[nf][tf][2]); sk.w = f2b(aK[nf][tf][3]);
            *reinterpret_cast<short4*>(&Q[o]) = sq;
            *reinterpret_cast<short4*>(&K[o]) = sk;
        }
    #pragma unroll
    for (int tf = 0; tf < 2; ++tf)
        #pragma unroll
        for (int df = 0; df < 4; ++df) {
            int d  = df * 16 + l15;
            int t4 = t0 + wid * 32 + tf * 16 + lg * 4;
            short4 sv;
            sv.x = f2b(aV[tf][df][0]); sv.y = f2b(aV[tf][df][1]);
            sv.z = f2b(aV[tf][df][2]); sv.w = f2b(aV[tf][df][3]);
            *reinterpret_cast<short4*>(&Vt[((size_t)b * NH + d) * NT + t4]) = sv;
        }
}

// ---------------------------------------------------------------------------
// Kernel B: mean over T of V per (batch, d) — degenerate-row fixup source.
// ---------------------------------------------------------------------------
__global__ __launch_bounds__(1024) void meanv_kernel(
    const __hip_bfloat16* __restrict__ Vt, float* __restrict__ MV)
{
    __shared__ float red[NH][17];
    const int b    = blockIdx.x;
    const int tid  = threadIdx.x;
    const int d    = tid >> 4;
    const int part = tid & 15;
    const __hip_bfloat16* row = Vt + ((size_t)b * NH + d) * NT;
    float s = 0.f;
    for (int t = part * 128; t < part * 128 + 128; t += 8) {
        bf16x8 v = *reinterpret_cast<const bf16x8*>(&row[t]);
        #pragma unroll
        for (int j = 0; j < 8; ++j) s += b2f(v[j]);
    }
    red[d][part] = s;
    __syncthreads();
    if (part == 0) {
        float tot = 0.f;
        #pragma unroll
        for (int i = 0; i < 16; ++i) tot += red[d][i];
        MV[b * NH + d] = tot * (1.0f / NT);
    }
}

// ---------------------------------------------------------------------------
// Online-softmax step (exp2 domain; scores pre-scaled; padding mask already in
// accumulator via bias init). Causal compare only when 'causal' is true.
// ---------------------------------------------------------------------------
static __device__ inline void sm_step(
    bool causal, int q, int k0, const int (&koff)[4],
    const f32x4 (&s)[4], float& m_r, float& l_r, float& al,
    bf16x8& pb0, bf16x8& pb1)
{
    float y[4][4];
    #pragma unroll
    for (int jt = 0; jt < 4; ++jt)
        #pragma unroll
        for (int r = 0; r < 4; ++r) {
            float v = s[jt][r];
            if (causal && (k0 + koff[jt] + r > q)) v = LNEG;
            y[jt][r] = v;
        }
    float tm = y[0][0];
    #pragma unroll
    for (int jt = 0; jt < 4; ++jt)
        #pragma unroll
        for (int r = 0; r < 4; ++r) tm = fmaxf(tm, y[jt][r]);
    tm = fmaxf(tm, __shfl_xor(tm, 16));
    tm = fmaxf(tm, __shfl_xor(tm, 32));
    const float mnew = fmaxf(m_r, tm);
    al  = __builtin_amdgcn_exp2f(m_r - mnew);
    m_r = mnew;
    float p[4][4], rs = 0.f;
    #pragma unroll
    for (int jt = 0; jt < 4; ++jt)
        #pragma unroll
        for (int r = 0; r < 4; ++r) {
            p[jt][r] = __builtin_amdgcn_exp2f(y[jt][r] - mnew);
            rs += p[jt][r];
        }
    rs += __shfl_xor(rs, 16);
    rs += __shfl_xor(rs, 32);
    l_r = l_r * al + rs;
    #pragma unroll
    for (int r = 0; r < 4; ++r) {
        pb0[r]     = f2b(p[0][r]);
        pb0[4 + r] = f2b(p[1][r]);
        pb1[r]     = f2b(p[2][r]);
        pb1[4 + r] = f2b(p[3][r]);
    }
}

// ---------------------------------------------------------------------------
// Kernel C: swapped-operand bf16 MFMA flash attention, PAIRED q-tiles.
// Block = q-tiles {gA=pi, gB=31-pi} multiplexed over ONE shared K/V stream:
// K/V LDS fragments read once feed both groups (32 MFMA/tile when both live).
// XCD swizzle: bid&7 = XCD; 4 batches per XCD -> K/V L2-resident (2MB/XCD).
// LDS XOR swizzle: chunk' = chunk ^ ((row&3)|(((row>>3)&1)<<2)) -> conflict-
// free staging writes and fragment reads for both K and Vt patterns.
// ---------------------------------------------------------------------------
__global__ __launch_bounds__(256) void attn_kernel(
    const __hip_bfloat16* __restrict__ Q, const __hip_bfloat16* __restrict__ K,
    const __hip_bfloat16* __restrict__ Vt, const float* __restrict__ Bias,
    const float* __restrict__ MV, float* __restrict__ Out)
{
    __shared__ __hip_bfloat16 k_lds[KB][NH];     // row key, 16B chunks XOR-swz
    __shared__ __hip_bfloat16 vt_lds[NH][KB];    // row d,  16B chunks XOR-swz

    const int bid  = blockIdx.x;
    const int xcd  = bid & 7;
    const int slot = bid >> 3;                   // 0..63
    const int b    = xcd * 4 + (slot >> 4);      // 4 batches per XCD
    const int pi   = slot & 15;
    const int gA   = pi, gB = 31 - pi;           // paired q-tiles: uniform work

    const int tid  = threadIdx.x;
    const int wid  = tid >> 6;
    const int lane = tid & 63;
    const int l15  = lane & 15;
    const int lg   = lane >> 4;

    const __hip_bfloat16* Kg = K  + (size_t)b * NT * NH;
    const __hip_bfloat16* Vg = Vt + (size_t)b * NH * NT;
    const float* Bb = Bias + b * NT;

    const int qA = gA * QB + wid * 16 + l15;
    const int qB = gB * QB + wid * 16 + l15;
    bf16x8 qA0, qA1, qB0, qB1;
    {
        const __hip_bfloat16* Qr = Q + ((size_t)b * NT + qA) * NH;
        qA0 = *reinterpret_cast<const bf16x8*>(&Qr[lg * 8]);
        qA1 = *reinterpret_cast<const bf16x8*>(&Qr[lg * 8 + 32]);
        const __hip_bfloat16* Qs = Q + ((size_t)b * NT + qB) * NH;
        qB0 = *reinterpret_cast<const bf16x8*>(&Qs[lg * 8]);
        qB1 = *reinterpret_cast<const bf16x8*>(&Qs[lg * 8 + 32]);
    }

    f32x4 oA[4], oB[4];
    #pragma unroll
    for (int dt = 0; dt < 4; ++dt) {
        oA[dt] = (f32x4){0.f,0.f,0.f,0.f};
        oB[dt] = (f32x4){0.f,0.f,0.f,0.f};
    }
    float mA = -3.0e38f, lA = 0.f, mB = -3.0e38f, lB = 0.f;

    // fragment addressing (round-3 verified key map + XOR swizzle)
    int kr[4], koff[4];
    #pragma unroll
    for (int jt = 0; jt < 4; ++jt) {
        kr[jt]   = ((jt & 2) << 4) | ((l15 >> 2) << 3) | ((jt & 1) << 2) | (l15 & 3);
        koff[jt] = ((jt & 2) << 4) | (lg << 3) | ((jt & 1) << 2);
    }
    const int swk  = (l15 & 3) | (((l15 >> 2) & 1) << 2);  // sw(kr), jt-invariant
    const int swv  = (l15 & 3) | (((l15 >> 3) & 1) << 2);  // sw(vr), dt-invariant
    const int kch0 = ((lg ^ swk) & 7) * 8;
    const int vch0 = ((lg ^ swv) & 7) * 8;

    // staging coords: rows sr, sr+32 (sw identical); linear global chunk c
    const int sr  = tid >> 3;
    const int c   = tid & 7;
    const int sws = (sr & 3) | (((sr >> 3) & 1) << 2);
    const int scS = ((c ^ sws) & 7) * 8;         // LDS store chunk (swizzled)
    const int cg  = c * 8;                       // global chunk (linear)

    bf16x8 kp0 = *reinterpret_cast<const bf16x8*>(&Kg[(size_t)sr * NH + cg]);
    bf16x8 kp1 = *reinterpret_cast<const bf16x8*>(&Kg[(size_t)(sr + 32) * NH + cg]);
    bf16x8 vp0 = *reinterpret_cast<const bf16x8*>(&Vg[(size_t)sr * NT + cg]);
    bf16x8 vp1 = *reinterpret_cast<const bf16x8*>(&Vg[(size_t)(sr + 32) * NT + cg]);

    for (int kt = 0; kt <= gB; ++kt) {
        const int k0 = kt * KB;
        __syncthreads();
        *reinterpret_cast<bf16x8*>(&k_lds[sr][scS])       = kp0;
        *reinterpret_cast<bf16x8*>(&k_lds[sr + 32][scS])  = kp1;
        *reinterpret_cast<bf16x8*>(&vt_lds[sr][scS])      = vp0;
        *reinterpret_cast<bf16x8*>(&vt_lds[sr + 32][scS]) = vp1;
        __syncthreads();

        if (kt < gB) {                           // prefetch overlaps compute
            const int kn = k0 + KB;
            kp0 = *reinterpret_cast<const bf16x8*>(&Kg[(size_t)(kn + sr) * NH + cg]);
            kp1 = *reinterpret_cast<const bf16x8*>(&Kg[(size_t)(kn + sr + 32) * NH + cg]);
            vp0 = *reinterpret_cast<const bf16x8*>(&Vg[(size_t)sr * NT + kn + cg]);
            vp1 = *reinterpret_cast<const bf16x8*>(&Vg[(size_t)(sr + 32) * NT + kn + cg]);
        }

        const bool aAct = (kt <= gA);

        f32x4 bias4[4];
        #pragma unroll
        for (int jt = 0; jt < 4; ++jt)
            bias4[jt] = *reinterpret_cast<const f32x4*>(&Bb[k0 + koff[jt]]);

        // ---- QK^T: shared K fragments feed both groups ----
        f32x4 sA[4], sB[4];
        #pragma unroll
        for (int jt = 0; jt < 4; ++jt) {
            bf16x8 kfa = *reinterpret_cast<const bf16x8*>(&k_lds[kr[jt]][kch0]);
            bf16x8 kfb = *reinterpret_cast<const bf16x8*>(&k_lds[kr[jt]][kch0 ^ 32]);
            sB[jt] = __builtin_amdgcn_mfma_f32_16x16x32_bf16(kfa, qB0, bias4[jt], 0, 0, 0);
            sB[jt] = __builtin_amdgcn_mfma_f32_16x16x32_bf16(kfb, qB1, sB[jt], 0, 0, 0);
            if (aAct) {
                sA[jt] = __builtin_amdgcn_mfma_f32_16x16x32_bf16(kfa, qA0, bias4[jt], 0, 0, 0);
                sA[jt] = __builtin_amdgcn_mfma_f32_16x16x32_bf16(kfb, qA1, sA[jt], 0, 0, 0);
            }
        }

        float alA = 1.f, alB;
        bf16x8 pA0, pA1, pB0, pB1;
        sm_step(kt == gB, qB, k0, koff, sB, mB, lB, alB, pB0, pB1);
        if (aAct)
            sm_step(kt == gA, qA, k0, koff, sA, mA, lA, alA, pA0, pA1);

        // ---- PV: shared V fragments feed both groups ----
        #pragma unroll
        for (int dt = 0; dt < 4; ++dt) {
            bf16x8 vfa = *reinterpret_cast<const bf16x8*>(&vt_lds[dt * 16 + l15][vch0]);
            bf16x8 vfb = *reinterpret_cast<const bf16x8*>(&vt_lds[dt * 16 + l15][vch0 ^ 32]);
            #pragma unroll
            for (int r = 0; r < 4; ++r) oB[dt][r] *= alB;
            oB[dt] = __builtin_amdgcn_mfma_f32_16x16x32_bf16(vfa, pB0, oB[dt], 0, 0, 0);
            oB[dt] = __builtin_amdgcn_mfma_f32_16x16x32_bf16(vfb, pB1, oB[dt], 0, 0, 0);
            if (aAct) {
                #pragma unroll
                for (int r = 0; r < 4; ++r) oA[dt][r] *= alA;
                oA[dt] = __builtin_amdgcn_mfma_f32_16x16x32_bf16(vfa, pA0, oA[dt], 0, 0, 0);
                oA[dt] = __builtin_amdgcn_mfma_f32_16x16x32_bf16(vfb, pA1, oA[dt], 0, 0, 0);
            }
        }
    }

    // ---- epilogue: normalize; degenerate rows -> mean V ----
    #pragma unroll
    for (int grp = 0; grp < 2; ++grp) {
        const int   q  = grp ? qB : qA;
        const float m  = grp ? mB : mA;
        const float l  = grp ? lB : lA;
        const f32x4* o = grp ? oB : oA;
        const bool degen = (m <= -5.0e8f);
        const float inv  = degen ? 0.f : 1.0f / l;
        float* Or = Out + ((size_t)b * NT + q) * NH;
        #pragma unroll
        for (int dt = 0; dt < 4; ++dt) {
            float4 ov;
            if (degen) {
                ov = *reinterpret_cast<const float4*>(&MV[b * NH + dt * 16 + lg * 4]);
            } else {
                ov.x = o[dt][0] * inv; ov.y = o[dt][1] * inv;
                ov.z = o[dt][2] * inv; ov.w = o[dt][3] * inv;
            }
            *reinterpret_cast<float4*>(&Or[dt * 16 + lg * 4]) = ov;
        }
    }
}

// ---------------------------------------------------------------------------
extern "C" void kernel_launch(void* const* d_in, const int* in_sizes, int n_in,
                              void* d_out, int out_size, void* d_ws, size_t ws_size,
                              hipStream_t stream)
{
    const float* X  = (const float*)d_in[0];   // q_input (B,T,C) fp32
    const float* Wq = (const float*)d_in[1];
    const float* Wk = (const float*)d_in[2];
    const float* Wv = (const float*)d_in[3];
    const int*   M  = (const int*)d_in[4];     // attn_mask (B,T) int32
    float* out = (float*)d_out;                // (B,T,HS) fp32

    __hip_bfloat16* Qp = (__hip_bfloat16*)d_ws;
    __hip_bfloat16* Kp = Qp + (size_t)NB * NT * NH;
    __hip_bfloat16* Vp = Kp + (size_t)NB * NT * NH;
    float* MVp = (float*)(Vp + (size_t)NB * NT * NH);
    __hip_bfloat16* Wtp = (__hip_bfloat16*)(MVp + NB * NH);
    float* Biasp = (float*)(Wtp + 192 * NC);

    wprep_kernel<<<192, 256, 0, stream>>>(Wq, Wk, Wv, Wtp);
    biasprep_kernel<<<NB * NT / 256, 256, 0, stream>>>(M, Biasp);
    qkv_kernel<<<NB * NT / MT, 256, 0, stream>>>(X, Wtp, Qp, Kp, Vp);
    meanv_kernel<<<NB, 1024, 0, stream>>>(Vp, MVp);
    attn_kernel<<<512, 256, 0, stream>>>(Qp, Kp, Vp, Biasp, MVp, out);
}